// Round 4
// baseline (806.650 us; speedup 1.0000x reference)
//
#include <hip/hip_runtime.h>
#include <hip/hip_bf16.h>
#include <stdint.h>

typedef __attribute__((ext_vector_type(4))) float  floatx4;
typedef __attribute__((ext_vector_type(8))) short  shortx8;

__device__ __forceinline__ unsigned short f2bf(float f) {
    unsigned int u = __builtin_bit_cast(unsigned int, f);
    u += 0x7FFFu + ((u >> 16) & 1u);
    return (unsigned short)(u >> 16);
}
__device__ __forceinline__ float bf2f(unsigned short h) {
    unsigned int u = (unsigned int)h << 16;
    return __builtin_bit_cast(float, u);
}

__device__ __forceinline__ uint4 pack8(float4 a, float4 b) {
    uint4 r;
    r.x = (unsigned)f2bf(a.x) | ((unsigned)f2bf(a.y) << 16);
    r.y = (unsigned)f2bf(a.z) | ((unsigned)f2bf(a.w) << 16);
    r.z = (unsigned)f2bf(b.x) | ((unsigned)f2bf(b.y) << 16);
    r.w = (unsigned)f2bf(b.z) | ((unsigned)f2bf(b.w) << 16);
    return r;
}

// async global->LDS, 16B per lane. LDS dest must be (wave-uniform base + lane*16).
__device__ __forceinline__ void gload16(const ushort* g, ushort* l) {
    __builtin_amdgcn_global_load_lds(
        (const __attribute__((address_space(1))) unsigned int*)g,
        (__attribute__((address_space(3))) unsigned int*)l, 16, 0, 0);
}

// ------- merged cast+pack: memory->bf16, decoder->concat left, mask->bits -------
__global__ __launch_bounds__(256) void cast_pack(const float* __restrict__ mem,
                                                 const float* __restrict__ dec,
                                                 const int* __restrict__ mask,
                                                 ushort* __restrict__ mem_bf,
                                                 ushort* __restrict__ concat,
                                                 unsigned long long* __restrict__ mb) {
    int bx = blockIdx.x;
    if (bx < 4096) {
        long long i = ((long long)bx * 256 + threadIdx.x) * 8;
        const float4* p = (const float4*)(mem + i);
        *(uint4*)(mem_bf + i) = pack8(p[0], p[1]);
    } else if (bx < 8192) {
        long long i = ((long long)(bx - 4096) * 256 + threadIdx.x) * 8;
        long long r = i >> 10, c = i & 1023;
        const float4* p = (const float4*)(dec + i);
        *(uint4*)(concat + r * 2048 + c) = pack8(p[0], p[1]);
    } else {
        int gw = ((bx - 8192) * 256 + threadIdx.x) >> 6;   // 0..8191
        int l = threadIdx.x & 63;
        #pragma unroll
        for (int i = 0; i < 16; ++i) {
            size_t widx = (size_t)gw * 16 + i;
            unsigned long long m = __ballot(mask[widx * 64 + l] != 0);
            if (l == 0) mb[widx] = m;
        }
    }
}

// ------- all weight transpose-casts in one launch: z 0-2 = 1024^2, z 3-4 = Wf halves ---
__global__ __launch_bounds__(256) void wtrans_all(const float* __restrict__ W0,
                                                  const float* __restrict__ W1,
                                                  const float* __restrict__ W2,
                                                  const float* __restrict__ W3,
                                                  ushort* __restrict__ T0,
                                                  ushort* __restrict__ T1,
                                                  ushort* __restrict__ T2,
                                                  ushort* __restrict__ T3) {
    __shared__ float t[32][33];
    int z = blockIdx.z;
    const float* W; ushort* WT; int K, byb;
    if (z == 0)      { W = W0; WT = T0; K = 1024; byb = blockIdx.y; }
    else if (z == 1) { W = W1; WT = T1; K = 1024; byb = blockIdx.y; }
    else if (z == 2) { W = W2; WT = T2; K = 1024; byb = blockIdx.y; }
    else             { W = W3; WT = T3; K = 2048; byb = blockIdx.y + (z - 3) * 32; }
    int tx = threadIdx.x, ty = threadIdx.y;
    int bx = blockIdx.x * 32;   // n
    int by = byb * 32;          // k
    #pragma unroll
    for (int i = 0; i < 4; i++)
        t[ty + 8 * i][tx] = W[(size_t)(by + ty + 8 * i) * 1024 + bx + tx];
    __syncthreads();
    #pragma unroll
    for (int i = 0; i < 4; i++)
        WT[(size_t)(bx + ty + 8 * i) * K + by + tx] = f2bf(t[tx][ty + 8 * i]);
}

// ---------------- V transpose per (b,h): V[(b*1024+k)*1024+h*128+d] -> VT[((h*8+b)*128+d)*1024+k]
__global__ __launch_bounds__(256) void vtrans(const ushort* __restrict__ V,
                                              ushort* __restrict__ VT) {
    __shared__ ushort t[32][33];
    int tx = threadIdx.x, ty = threadIdx.y;
    int bk = blockIdx.x * 32;  // k
    int bd = blockIdx.y * 32;  // d
    int z = blockIdx.z;
    int b = z >> 3, h = z & 7;
    #pragma unroll
    for (int i = 0; i < 4; i++)
        t[ty + 8 * i][tx] = V[((size_t)(b * 1024 + bk + ty + 8 * i)) * 1024 + h * 128 + bd + tx];
    __syncthreads();
    #pragma unroll
    for (int i = 0; i < 4; i++)
        VT[((size_t)((h * 8 + b) * 128 + bd + ty + 8 * i)) * 1024 + bk + tx] = t[tx][ty + 8 * i];
}

// ---------------- shared GEMM core: C[m][n] = sum_k A[m][k]*Bt[n][k] --------------------
// m97 structure: 128x128 tile, BK=64, linear LDS, global_load_lds staging, 2-barrier loop.
template <typename TC>
__device__ __forceinline__ void gemm_core(ushort* As, ushort* Bs,
                                          const ushort* __restrict__ A,
                                          const ushort* __restrict__ Bt, TC* __restrict__ C,
                                          int kbeg, int kend, int lda, int ldb, int ldc,
                                          int bm, int bn) {
    int tid = threadIdx.x;
    int l = tid & 63, wid = tid >> 6;
    int l16 = l & 15, quad = l >> 4;
    int wm = (wid & 1) * 64, wn = (wid >> 1) * 64;
    int srow = tid >> 3;          // 0..31
    int scol = (tid & 7) * 8;     // 0..56

    floatx4 acc[4][4];
    #pragma unroll
    for (int i = 0; i < 4; i++)
        #pragma unroll
        for (int j = 0; j < 4; j++)
            acc[i][j] = {0.0f, 0.0f, 0.0f, 0.0f};

    for (int kt = kbeg; kt < kend; kt += 64) {
        #pragma unroll
        for (int it = 0; it < 4; it++) {
            int row = it * 32 + srow;
            gload16(A + (size_t)(bm + row) * lda + kt + scol, &As[row * 64 + scol]);
            gload16(Bt + (size_t)(bn + row) * ldb + kt + scol, &Bs[row * 64 + scol]);
        }
        __syncthreads();
        #pragma unroll
        for (int kk = 0; kk < 64; kk += 32) {
            shortx8 af[4], bfr[4];
            #pragma unroll
            for (int i = 0; i < 4; i++)
                af[i] = *(const shortx8*)&As[(wm + i * 16 + l16) * 64 + kk + quad * 8];
            #pragma unroll
            for (int j = 0; j < 4; j++)
                bfr[j] = *(const shortx8*)&Bs[(wn + j * 16 + l16) * 64 + kk + quad * 8];
            #pragma unroll
            for (int i = 0; i < 4; i++)
                #pragma unroll
                for (int j = 0; j < 4; j++)
                    acc[i][j] = __builtin_amdgcn_mfma_f32_16x16x32_bf16(af[i], bfr[j], acc[i][j], 0, 0, 0);
        }
        __syncthreads();
    }

    #pragma unroll
    for (int i = 0; i < 4; i++) {
        #pragma unroll
        for (int j = 0; j < 4; j++) {
            int row0 = bm + wm + i * 16 + quad * 4;
            int col = bn + wn + j * 16 + l16;
            #pragma unroll
            for (int r = 0; r < 4; r++) {
                float v = acc[i][j][r];
                size_t idx = (size_t)(row0 + r) * ldc + col;
                if constexpr (__is_same(TC, float)) C[idx] = v;
                else C[idx] = f2bf(v);
            }
        }
    }
}

// three projections, 1D grid with XCD-aware decode: each XCD owns 8 m-panels x all n
__global__ __launch_bounds__(256) void gemm_proj3(
    const ushort* __restrict__ mem_bf, const ushort* __restrict__ concat,
    const ushort* __restrict__ WkT, const ushort* __restrict__ WvT,
    const ushort* __restrict__ WqT,
    ushort* __restrict__ Kp, ushort* __restrict__ Vp, ushort* __restrict__ Qp) {
    __shared__ ushort As[128 * 64];
    __shared__ ushort Bs[128 * 64];
    int bid = blockIdx.x;
    int z = bid >> 9;             // 0..2
    int r = bid & 511;
    int xcd = r & 7, i = r >> 3;  // i: m fastest within 8-panel group, then n
    int m = xcd * 8 + (i & 7), n = i >> 3;
    const ushort* A; const ushort* Bt; ushort* C; int lda;
    if (z == 0)      { A = mem_bf; Bt = WkT; C = Kp; lda = 1024; }
    else if (z == 1) { A = mem_bf; Bt = WvT; C = Vp; lda = 1024; }
    else             { A = concat; Bt = WqT; C = Qp; lda = 2048; }
    gemm_core<ushort>(As, Bs, A, Bt, C, 0, 1024, lda, 1024, 1024, m * 128, n * 128);
}

// FFN split-K (z halves of K=2048), same XCD-aware decode
__global__ __launch_bounds__(256) void gemm_ffn(
    const ushort* __restrict__ concat, const ushort* __restrict__ WfT,
    float* __restrict__ ffn0, float* __restrict__ ffn1) {
    __shared__ ushort As[128 * 64];
    __shared__ ushort Bs[128 * 64];
    int bid = blockIdx.x;
    int z = bid >> 9;
    int r = bid & 511;
    int xcd = r & 7, i = r >> 3;
    int m = xcd * 8 + (i & 7), n = i >> 3;
    gemm_core<float>(As, Bs, concat, WfT, z ? ffn1 : ffn0,
                     z * 1024, z * 1024 + 1024, 2048, 2048, 1024, m * 128, n * 128);
}

// ---------------- fused attention: QK^T -> mask -> softmax -> *qmask -> attns + PV ------
// Phase order is the key fix this round: QK -> rowsum -> PV (MFMA+loads) -> THEN the
// 64KB attns stream-out. vmcnt retires in issue order, so any store issued before a
// load-wait serializes the compute behind the HBM store drain. All stores now come
// after the last load-wait. Plain (cached) stores: ack at L2, drain in background.
__global__ __launch_bounds__(256, 4) void fused_attn(
    const ushort* __restrict__ Qp, const ushort* __restrict__ Kp,
    const ushort* __restrict__ VT, const unsigned long long* __restrict__ mb,
    const float* __restrict__ qmask, float* __restrict__ attns,
    ushort* __restrict__ concat) {
    __shared__ ushort Qs[16 * 136];        // Q tile
    __shared__ ushort Ss[16 * 1032];       // exp'd scores bf16, stride 1032 (pad 8)
    __shared__ unsigned Ms[16][34];        // bitpacked mask tile (16 rows x 32 words)
    __shared__ float rowpart[16][5];
    __shared__ float scale_s[16];

    int bid = blockIdx.x;
    const int h = bid & 7;                 // XCD-pinned head (FETCH 140->29MB, keep)
    int t = bid >> 3;
    const int b = t >> 6;                  // b slowest: K(b,h) hot across 64 q-blocks
    const int q0 = (t & 63) * 16;
    const int tid = threadIdx.x;
    const int w = tid >> 6, l = tid & 63;
    const int l16 = l & 15, quad = l >> 4;
    const float sc = 0.08838834764831845f;  // 1/sqrt(128)

    // ---- load Q tile (16 x 128) + mask tile (16 x 2 uint64) ----
    {
        int row = tid >> 4, col = (tid & 15) * 8;
        *(uint4*)&Qs[row * 136 + col] =
            *(const uint4*)(Qp + (size_t)(b * 1024 + q0 + row) * 1024 + h * 128 + col);
        int pr = tid & 15;
        uint2 mv = ((const uint2*)mb)[(size_t)(b * 1024 + q0 + row) * 16 + pr];
        Ms[row][pr * 2] = mv.x;
        Ms[row][pr * 2 + 1] = mv.y;
    }
    __syncthreads();

    // preload A-fragments (reused for all k-tiles)
    shortx8 af[4];
    #pragma unroll
    for (int kk = 0; kk < 4; kk++)
        af[kk] = *(const shortx8*)&Qs[l16 * 136 + kk * 32 + quad * 8];

    // ---- QK^T + mask + exp, depth-2 pipelined K loads, fused row-sums ----
    const ushort* Kb = Kp + (size_t)(b * 1024 + w * 16 + l16) * 1024 + h * 128 + quad * 8;
#define KLD(c, o) (*(const shortx8*)(Kb + (size_t)(c) * 65536 + (o)))
    shortx8 ka0 = KLD(0, 0), ka1 = KLD(0, 32), ka2 = KLD(0, 64), ka3 = KLD(0, 96);
    shortx8 kb0 = KLD(1, 0), kb1 = KLD(1, 32), kb2 = KLD(1, 64), kb3 = KLD(1, 96);
    float ssum[4] = {0.0f, 0.0f, 0.0f, 0.0f};
    const int bp64 = w * 16 + l16;
    const int wsel = bp64 >> 5, bitp = bp64 & 31;
    #pragma unroll 1
    for (int cc = 0; cc < 16; cc += 2) {
        int c2 = cc + 2 < 16 ? cc + 2 : 14;
        int c3 = cc + 3 < 16 ? cc + 3 : 15;
        shortx8 n0 = KLD(c2, 0), n1 = KLD(c2, 32), n2 = KLD(c2, 64), n3 = KLD(c2, 96);
        floatx4 acc = {0.0f, 0.0f, 0.0f, 0.0f};
        __builtin_amdgcn_s_setprio(1);
        acc = __builtin_amdgcn_mfma_f32_16x16x32_bf16(af[0], ka0, acc, 0, 0, 0);
        acc = __builtin_amdgcn_mfma_f32_16x16x32_bf16(af[1], ka1, acc, 0, 0, 0);
        acc = __builtin_amdgcn_mfma_f32_16x16x32_bf16(af[2], ka2, acc, 0, 0, 0);
        acc = __builtin_amdgcn_mfma_f32_16x16x32_bf16(af[3], ka3, acc, 0, 0, 0);
        __builtin_amdgcn_s_setprio(0);
        {
            int k0 = cc * 64 + w * 16;
            #pragma unroll
            for (int r = 0; r < 4; ++r) {
                int q = quad * 4 + r;
                unsigned wv = Ms[q][cc * 2 + wsel];
                float v = ((wv >> bitp) & 1u) ? 0.0f : __expf(acc[r] * sc);
                ssum[r] += v;
                Ss[q * 1032 + k0 + l16] = f2bf(v);
            }
        }
        shortx8 m0 = KLD(c3, 0), m1 = KLD(c3, 32), m2 = KLD(c3, 64), m3 = KLD(c3, 96);
        floatx4 acc2 = {0.0f, 0.0f, 0.0f, 0.0f};
        __builtin_amdgcn_s_setprio(1);
        acc2 = __builtin_amdgcn_mfma_f32_16x16x32_bf16(af[0], kb0, acc2, 0, 0, 0);
        acc2 = __builtin_amdgcn_mfma_f32_16x16x32_bf16(af[1], kb1, acc2, 0, 0, 0);
        acc2 = __builtin_amdgcn_mfma_f32_16x16x32_bf16(af[2], kb2, acc2, 0, 0, 0);
        acc2 = __builtin_amdgcn_mfma_f32_16x16x32_bf16(af[3], kb3, acc2, 0, 0, 0);
        __builtin_amdgcn_s_setprio(0);
        {
            int k0 = (cc + 1) * 64 + w * 16;
            #pragma unroll
            for (int r = 0; r < 4; ++r) {
                int q = quad * 4 + r;
                unsigned wv = Ms[q][(cc + 1) * 2 + wsel];
                float v = ((wv >> bitp) & 1u) ? 0.0f : __expf(acc2[r] * sc);
                ssum[r] += v;
                Ss[q * 1032 + k0 + l16] = f2bf(v);
            }
        }
        ka0 = n0; ka1 = n1; ka2 = n2; ka3 = n3;
        kb0 = m0; kb1 = m1; kb2 = m2; kb3 = m3;
    }
#undef KLD

    // ---- reduce row-sums: butterfly over the 16-lane group, combine 4 waves via LDS ----
    #pragma unroll
    for (int r = 0; r < 4; ++r) {
        float s = ssum[r];
        #pragma unroll
        for (int off = 1; off < 16; off <<= 1) s += __shfl_xor(s, off, 16);
        ssum[r] = s;
    }
    if (l16 == 0) {
        #pragma unroll
        for (int r = 0; r < 4; ++r) rowpart[quad * 4 + r][w] = ssum[r];
    }
    __syncthreads();
    if (tid < 16) {
        float s = rowpart[tid][0] + rowpart[tid][1] + rowpart[tid][2] + rowpart[tid][3];
        scale_s[tid] = qmask[b * 1024 + q0 + tid] / s;
    }
    __syncthreads();

    // ---- PV FIRST: O = P @ V, depth-2 pipelined V-frag loads, NO stores in flight ----
    const size_t vrow0 = (size_t)((h * 8 + b) * 128 + w * 32);
    const ushort* Vb0 = VT + (vrow0 + l16) * 1024 + quad * 8;
    const ushort* Vb1 = VT + (vrow0 + 16 + l16) * 1024 + quad * 8;
#define VLD(p, c, o) (*(const shortx8*)((p) + (c) * 64 + (o)))
    shortx8 va0 = VLD(Vb0, 0, 0), va1 = VLD(Vb1, 0, 0);
    shortx8 va2 = VLD(Vb0, 0, 32), va3 = VLD(Vb1, 0, 32);
    shortx8 vb0 = VLD(Vb0, 1, 0), vb1 = VLD(Vb1, 1, 0);
    shortx8 vb2 = VLD(Vb0, 1, 32), vb3 = VLD(Vb1, 1, 32);
    floatx4 o0 = {0.0f, 0.0f, 0.0f, 0.0f}, o1 = {0.0f, 0.0f, 0.0f, 0.0f};
    #pragma unroll 1
    for (int cc = 0; cc < 16; cc += 2) {
        int c2 = cc + 2 < 16 ? cc + 2 : 14;
        int c3 = cc + 3 < 16 ? cc + 3 : 15;
        shortx8 n0 = VLD(Vb0, c2, 0), n1 = VLD(Vb1, c2, 0);
        shortx8 n2 = VLD(Vb0, c2, 32), n3 = VLD(Vb1, c2, 32);
        shortx8 pa0 = *(const shortx8*)&Ss[l16 * 1032 + cc * 64 + quad * 8];
        shortx8 pa1 = *(const shortx8*)&Ss[l16 * 1032 + cc * 64 + 32 + quad * 8];
        __builtin_amdgcn_s_setprio(1);
        o0 = __builtin_amdgcn_mfma_f32_16x16x32_bf16(pa0, va0, o0, 0, 0, 0);
        o1 = __builtin_amdgcn_mfma_f32_16x16x32_bf16(pa0, va1, o1, 0, 0, 0);
        o0 = __builtin_amdgcn_mfma_f32_16x16x32_bf16(pa1, va2, o0, 0, 0, 0);
        o1 = __builtin_amdgcn_mfma_f32_16x16x32_bf16(pa1, va3, o1, 0, 0, 0);
        __builtin_amdgcn_s_setprio(0);
        shortx8 m0 = VLD(Vb0, c3, 0), m1 = VLD(Vb1, c3, 0);
        shortx8 m2 = VLD(Vb0, c3, 32), m3 = VLD(Vb1, c3, 32);
        shortx8 pb0 = *(const shortx8*)&Ss[l16 * 1032 + (cc + 1) * 64 + quad * 8];
        shortx8 pb1 = *(const shortx8*)&Ss[l16 * 1032 + (cc + 1) * 64 + 32 + quad * 8];
        __builtin_amdgcn_s_setprio(1);
        o0 = __builtin_amdgcn_mfma_f32_16x16x32_bf16(pb0, vb0, o0, 0, 0, 0);
        o1 = __builtin_amdgcn_mfma_f32_16x16x32_bf16(pb0, vb1, o1, 0, 0, 0);
        o0 = __builtin_amdgcn_mfma_f32_16x16x32_bf16(pb1, vb2, o0, 0, 0, 0);
        o1 = __builtin_amdgcn_mfma_f32_16x16x32_bf16(pb1, vb3, o1, 0, 0, 0);
        __builtin_amdgcn_s_setprio(0);
        va0 = n0; va1 = n1; va2 = n2; va3 = n3;
        vb0 = m0; vb1 = m1; vb2 = m2; vb3 = m3;
    }
#undef VLD

    // ---- all stores last: concat (small) then the 64KB/block attns stream ----
    #pragma unroll
    for (int r = 0; r < 4; ++r) {
        int q = quad * 4 + r;
        float scl = scale_s[q];
        int d = w * 32 + l16;
        size_t base = (size_t)(b * 1024 + q0 + q) * 2048 + 1024 + h * 128;
        concat[base + d]      = f2bf(o0[r] * scl);
        concat[base + d + 16] = f2bf(o1[r] * scl);
    }
    {
        int row = tid >> 4;
        float scl = scale_s[row];
        float* arow = attns + ((size_t)((h * 8 + b) * 1024 + q0 + row)) * 1024;
        int c0 = (tid & 15) * 8;
        #pragma unroll
        for (int j = 0; j < 8; ++j) {
            int c = c0 + j * 128;
            shortx8 v = *(const shortx8*)&Ss[row * 1032 + c];
            float4 oa, ob;
            oa.x = bf2f((unsigned short)v[0]) * scl;
            oa.y = bf2f((unsigned short)v[1]) * scl;
            oa.z = bf2f((unsigned short)v[2]) * scl;
            oa.w = bf2f((unsigned short)v[3]) * scl;
            ob.x = bf2f((unsigned short)v[4]) * scl;
            ob.y = bf2f((unsigned short)v[5]) * scl;
            ob.z = bf2f((unsigned short)v[6]) * scl;
            ob.w = bf2f((unsigned short)v[7]) * scl;
            *(float4*)(arow + c) = oa;
            *(float4*)(arow + c + 4) = ob;
        }
    }
}

// ---------------- LayerNorm epilogue: x = LN(ffn0 + ffn1 + bf + decoder) ----------------
__global__ __launch_bounds__(256) void ln_out(const float* __restrict__ ffn0,
                                              const float* __restrict__ ffn1,
                                              const float* __restrict__ dec,
                                              const float* __restrict__ bfv,
                                              const float* __restrict__ gamma,
                                              const float* __restrict__ beta,
                                              float* __restrict__ out) {
    __shared__ float sb[8];
    int row = blockIdx.x, tid = threadIdx.x;
    int c = tid * 4;
    size_t base = (size_t)row * 1024 + c;
    float4 x = *(const float4*)(ffn0 + base);
    float4 y = *(const float4*)(ffn1 + base);
    float4 d = *(const float4*)(dec + base);
    float4 bb = *(const float4*)(bfv + c);
    x.x += y.x + d.x + bb.x; x.y += y.y + d.y + bb.y;
    x.z += y.z + d.z + bb.z; x.w += y.w + d.w + bb.w;

    float s = x.x + x.y + x.z + x.w;
    float s2 = x.x * x.x + x.y * x.y + x.z * x.z + x.w * x.w;
    #pragma unroll
    for (int o = 32; o; o >>= 1) {
        s += __shfl_down(s, o, 64);
        s2 += __shfl_down(s2, o, 64);
    }
    if ((tid & 63) == 0) { sb[tid >> 6] = s; sb[4 + (tid >> 6)] = s2; }
    __syncthreads();
    s = sb[0] + sb[1] + sb[2] + sb[3];
    s2 = sb[4] + sb[5] + sb[6] + sb[7];
    float mu = s * (1.0f / 1024.0f);
    float var = s2 * (1.0f / 1024.0f) - mu * mu;
    float rs = rsqrtf(var + 1e-5f);

    float4 g = *(const float4*)(gamma + c);
    float4 be = *(const float4*)(beta + c);
    float4 o4;
    o4.x = (x.x - mu) * rs * g.x + be.x;
    o4.y = (x.y - mu) * rs * g.y + be.y;
    o4.z = (x.z - mu) * rs * g.z + be.z;
    o4.w = (x.w - mu) * rs * g.w + be.w;
    *(float4*)(out + base) = o4;
}

extern "C" void kernel_launch(void* const* d_in, const int* in_sizes, int n_in,
                              void* d_out, int out_size, void* d_ws, size_t ws_size,
                              hipStream_t stream) {
    const float* memory  = (const float*)d_in[0];   // (8,1024,1024)
    const float* decoder = (const float*)d_in[1];   // (8,1024,1024)
    const float* qmask   = (const float*)d_in[2];   // (8,1024)
    const float* Wk      = (const float*)d_in[3];   // (1024,1024)
    const float* Wv      = (const float*)d_in[4];
    const float* Wq      = (const float*)d_in[5];
    const float* Wf      = (const float*)d_in[6];   // (2048,1024)
    const float* bfv     = (const float*)d_in[7];   // (1024,)
    const float* gamma   = (const float*)d_in[8];
    const float* beta    = (const float*)d_in[9];
    const int*   mask    = (const int*)d_in[10];    // (8,1024,1024) 0/1

    float* xout  = (float*)d_out;                   // (8,1024,1024)
    float* attns = xout + 8388608LL;                // (64,1024,1024)

    char* w = (char*)d_ws;
    ushort* mem_bf = (ushort*)(w + 0);              // 16 MB [cast -> proj]
    ushort* Kp     = (ushort*)(w + (16LL << 20));   // 16 MB [proj -> fused]
    ushort* Qp     = (ushort*)(w + (32LL << 20));   // 16 MB [proj -> fused]
    ushort* Vp     = (ushort*)(w + (48LL << 20));   // 16 MB [proj -> vtrans]
    ushort* VT     = (ushort*)(w + (64LL << 20));   // 16 MB [vtrans -> fused]
    ushort* concat = (ushort*)(w + (80LL << 20));   // 32 MB [cast -> ffn]
    ushort* WkT    = (ushort*)(w + (112LL << 20));  // 2 MB
    ushort* WvT    = (ushort*)(w + (114LL << 20));  // 2 MB
    ushort* WqT    = (ushort*)(w + (116LL << 20));  // 2 MB
    ushort* WfT    = (ushort*)(w + (118LL << 20));  // 4 MB
    unsigned long long* mbits = (unsigned long long*)(w + (122LL << 20));  // 1 MB [cast -> fused]
    // overlays (lifetime-disjoint):
    float* ffn0 = (float*)(w + 0);                  // 32 MB over mem_bf+Kp (dead after fused)
    float* ffn1 = (float*)(w + (32LL << 20));       // 32 MB over Qp+Vp (dead after fused)

    // 1) casts + mask bitpack (merged)
    cast_pack<<<10240, 256, 0, stream>>>(memory, decoder, mask, mem_bf, concat, mbits);
    // 2) all weight transposes (one launch)
    wtrans_all<<<dim3(32, 32, 5), dim3(32, 8), 0, stream>>>(Wk, Wv, Wq, Wf, WkT, WvT, WqT, WfT);
    // 3) three projections, XCD-swizzled
    gemm_proj3<<<1536, 256, 0, stream>>>(mem_bf, concat, WkT, WvT, WqT, Kp, Vp, Qp);
    // 4) V transpose per (b,h)
    vtrans<<<dim3(32, 4, 64), dim3(32, 8), 0, stream>>>(Vp, VT);
    // 5) fused QK^T+softmax+qmask -> attns, and PV -> concat right half (XCD-swizzled)
    fused_attn<<<4096, 256, 0, stream>>>(Qp, Kp, VT, mbits, qmask, attns, concat);
    // 6) FFN split-K, XCD-swizzled
    gemm_ffn<<<1024, 256, 0, stream>>>(concat, WfT, ffn0, ffn1);
    // 7) bias + residual + LayerNorm -> x output
    ln_out<<<8192, 256, 0, stream>>>(ffn0, ffn1, decoder, bfv, gamma, beta, xout);
}

// Round 6
// 752.004 us; speedup vs baseline: 1.0727x; 1.0727x over previous
//
#include <hip/hip_runtime.h>
#include <hip/hip_bf16.h>
#include <stdint.h>

typedef __attribute__((ext_vector_type(4))) float  floatx4;
typedef __attribute__((ext_vector_type(8))) short  shortx8;

__device__ __forceinline__ unsigned short f2bf(float f) {
    unsigned int u = __builtin_bit_cast(unsigned int, f);
    u += 0x7FFFu + ((u >> 16) & 1u);
    return (unsigned short)(u >> 16);
}
__device__ __forceinline__ float bf2f(unsigned short h) {
    unsigned int u = (unsigned int)h << 16;
    return __builtin_bit_cast(float, u);
}

__device__ __forceinline__ uint4 pack8(float4 a, float4 b) {
    uint4 r;
    r.x = (unsigned)f2bf(a.x) | ((unsigned)f2bf(a.y) << 16);
    r.y = (unsigned)f2bf(a.z) | ((unsigned)f2bf(a.w) << 16);
    r.z = (unsigned)f2bf(b.x) | ((unsigned)f2bf(b.y) << 16);
    r.w = (unsigned)f2bf(b.z) | ((unsigned)f2bf(b.w) << 16);
    return r;
}

// async global->LDS, 16B per lane. LDS dest must be (wave-uniform base + lane*16).
__device__ __forceinline__ void gload16(const ushort* g, ushort* l) {
    __builtin_amdgcn_global_load_lds(
        (const __attribute__((address_space(1))) unsigned int*)g,
        (__attribute__((address_space(3))) unsigned int*)l, 16, 0, 0);
}

// ------- merged cast+pack: memory->bf16, decoder->concat left, mask->bits -------
__global__ __launch_bounds__(256) void cast_pack(const float* __restrict__ mem,
                                                 const float* __restrict__ dec,
                                                 const int* __restrict__ mask,
                                                 ushort* __restrict__ mem_bf,
                                                 ushort* __restrict__ concat,
                                                 unsigned long long* __restrict__ mb) {
    int bx = blockIdx.x;
    if (bx < 4096) {
        long long i = ((long long)bx * 256 + threadIdx.x) * 8;
        const float4* p = (const float4*)(mem + i);
        *(uint4*)(mem_bf + i) = pack8(p[0], p[1]);
    } else if (bx < 8192) {
        long long i = ((long long)(bx - 4096) * 256 + threadIdx.x) * 8;
        long long r = i >> 10, c = i & 1023;
        const float4* p = (const float4*)(dec + i);
        *(uint4*)(concat + r * 2048 + c) = pack8(p[0], p[1]);
    } else {
        int gw = ((bx - 8192) * 256 + threadIdx.x) >> 6;   // 0..8191
        int l = threadIdx.x & 63;
        #pragma unroll
        for (int i = 0; i < 16; ++i) {
            size_t widx = (size_t)gw * 16 + i;
            unsigned long long m = __ballot(mask[widx * 64 + l] != 0);
            if (l == 0) mb[widx] = m;
        }
    }
}

// ------- all weight transpose-casts in one launch: z 0-2 = 1024^2, z 3-4 = Wf halves ---
__global__ __launch_bounds__(256) void wtrans_all(const float* __restrict__ W0,
                                                  const float* __restrict__ W1,
                                                  const float* __restrict__ W2,
                                                  const float* __restrict__ W3,
                                                  ushort* __restrict__ T0,
                                                  ushort* __restrict__ T1,
                                                  ushort* __restrict__ T2,
                                                  ushort* __restrict__ T3) {
    __shared__ float t[32][33];
    int z = blockIdx.z;
    const float* W; ushort* WT; int K, byb;
    if (z == 0)      { W = W0; WT = T0; K = 1024; byb = blockIdx.y; }
    else if (z == 1) { W = W1; WT = T1; K = 1024; byb = blockIdx.y; }
    else if (z == 2) { W = W2; WT = T2; K = 1024; byb = blockIdx.y; }
    else             { W = W3; WT = T3; K = 2048; byb = blockIdx.y + (z - 3) * 32; }
    int tx = threadIdx.x, ty = threadIdx.y;
    int bx = blockIdx.x * 32;   // n
    int by = byb * 32;          // k
    #pragma unroll
    for (int i = 0; i < 4; i++)
        t[ty + 8 * i][tx] = W[(size_t)(by + ty + 8 * i) * 1024 + bx + tx];
    __syncthreads();
    #pragma unroll
    for (int i = 0; i < 4; i++)
        WT[(size_t)(bx + ty + 8 * i) * K + by + tx] = f2bf(t[tx][ty + 8 * i]);
}

// ---------------- V transpose per (b,h): V[(b*1024+k)*1024+h*128+d] -> VT[((h*8+b)*128+d)*1024+k]
__global__ __launch_bounds__(256) void vtrans(const ushort* __restrict__ V,
                                              ushort* __restrict__ VT) {
    __shared__ ushort t[32][33];
    int tx = threadIdx.x, ty = threadIdx.y;
    int bk = blockIdx.x * 32;  // k
    int bd = blockIdx.y * 32;  // d
    int z = blockIdx.z;
    int b = z >> 3, h = z & 7;
    #pragma unroll
    for (int i = 0; i < 4; i++)
        t[ty + 8 * i][tx] = V[((size_t)(b * 1024 + bk + ty + 8 * i)) * 1024 + h * 128 + bd + tx];
    __syncthreads();
    #pragma unroll
    for (int i = 0; i < 4; i++)
        VT[((size_t)((h * 8 + b) * 128 + bd + ty + 8 * i)) * 1024 + bk + tx] = t[tx][ty + 8 * i];
}

// ---------------- shared GEMM core: C[m][n] = sum_k A[m][k]*Bt[n][k] --------------------
template <typename TC>
__device__ __forceinline__ void gemm_core(ushort* As, ushort* Bs,
                                          const ushort* __restrict__ A,
                                          const ushort* __restrict__ Bt, TC* __restrict__ C,
                                          int kbeg, int kend, int lda, int ldb, int ldc,
                                          int bm, int bn) {
    int tid = threadIdx.x;
    int l = tid & 63, wid = tid >> 6;
    int l16 = l & 15, quad = l >> 4;
    int wm = (wid & 1) * 64, wn = (wid >> 1) * 64;
    int srow = tid >> 3;          // 0..31
    int scol = (tid & 7) * 8;     // 0..56

    floatx4 acc[4][4];
    #pragma unroll
    for (int i = 0; i < 4; i++)
        #pragma unroll
        for (int j = 0; j < 4; j++)
            acc[i][j] = {0.0f, 0.0f, 0.0f, 0.0f};

    for (int kt = kbeg; kt < kend; kt += 64) {
        #pragma unroll
        for (int it = 0; it < 4; it++) {
            int row = it * 32 + srow;
            gload16(A + (size_t)(bm + row) * lda + kt + scol, &As[row * 64 + scol]);
            gload16(Bt + (size_t)(bn + row) * ldb + kt + scol, &Bs[row * 64 + scol]);
        }
        __syncthreads();
        #pragma unroll
        for (int kk = 0; kk < 64; kk += 32) {
            shortx8 af[4], bfr[4];
            #pragma unroll
            for (int i = 0; i < 4; i++)
                af[i] = *(const shortx8*)&As[(wm + i * 16 + l16) * 64 + kk + quad * 8];
            #pragma unroll
            for (int j = 0; j < 4; j++)
                bfr[j] = *(const shortx8*)&Bs[(wn + j * 16 + l16) * 64 + kk + quad * 8];
            #pragma unroll
            for (int i = 0; i < 4; i++)
                #pragma unroll
                for (int j = 0; j < 4; j++)
                    acc[i][j] = __builtin_amdgcn_mfma_f32_16x16x32_bf16(af[i], bfr[j], acc[i][j], 0, 0, 0);
        }
        __syncthreads();
    }

    #pragma unroll
    for (int i = 0; i < 4; i++) {
        #pragma unroll
        for (int j = 0; j < 4; j++) {
            int row0 = bm + wm + i * 16 + quad * 4;
            int col = bn + wn + j * 16 + l16;
            #pragma unroll
            for (int r = 0; r < 4; r++) {
                float v = acc[i][j][r];
                size_t idx = (size_t)(row0 + r) * ldc + col;
                if constexpr (__is_same(TC, float)) C[idx] = v;
                else C[idx] = f2bf(v);
            }
        }
    }
}

// three projections, 1D grid with XCD-aware decode
__global__ __launch_bounds__(256) void gemm_proj3(
    const ushort* __restrict__ mem_bf, const ushort* __restrict__ concat,
    const ushort* __restrict__ WkT, const ushort* __restrict__ WvT,
    const ushort* __restrict__ WqT,
    ushort* __restrict__ Kp, ushort* __restrict__ Vp, ushort* __restrict__ Qp) {
    __shared__ ushort As[128 * 64];
    __shared__ ushort Bs[128 * 64];
    int bid = blockIdx.x;
    int z = bid >> 9;             // 0..2
    int r = bid & 511;
    int xcd = r & 7, i = r >> 3;
    int m = xcd * 8 + (i & 7), n = i >> 3;
    const ushort* A; const ushort* Bt; ushort* C; int lda;
    if (z == 0)      { A = mem_bf; Bt = WkT; C = Kp; lda = 1024; }
    else if (z == 1) { A = mem_bf; Bt = WvT; C = Vp; lda = 1024; }
    else             { A = concat; Bt = WqT; C = Qp; lda = 2048; }
    gemm_core<ushort>(As, Bs, A, Bt, C, 0, 1024, lda, 1024, 1024, m * 128, n * 128);
}

// FFN split-K (z halves of K=2048), same XCD-aware decode
__global__ __launch_bounds__(256) void gemm_ffn(
    const ushort* __restrict__ concat, const ushort* __restrict__ WfT,
    float* __restrict__ ffn0, float* __restrict__ ffn1) {
    __shared__ ushort As[128 * 64];
    __shared__ ushort Bs[128 * 64];
    int bid = blockIdx.x;
    int z = bid >> 9;
    int r = bid & 511;
    int xcd = r & 7, i = r >> 3;
    int m = xcd * 8 + (i & 7), n = i >> 3;
    gemm_core<float>(As, Bs, concat, WfT, z ? ffn1 : ffn0,
                     z * 1024, z * 1024 + 1024, 2048, 2048, 1024, m * 128, n * 128);
}

// ---------------- fused attention ----------------
// K and V tiles staged into DOUBLE-BUFFERED LDS via global_load_lds (T3-minimum).
// The HW DMA queue holds next-tile loads in flight across the compute phase (the
// compiler collapsed the VGPR software pipeline: VGPR=52). XCD pin kept so reads are
// L2-hits. All global stores at the very end.
// R5 BUG FIX: STAGE_V LDS chunk stride was rr*4096 ushorts (2x too big) -> buffer
// overflow into Ms/scale_s and misplaced V rows 64..127. Correct: rr*2048 ushorts
// (chunk = 256 threads x 8 ushorts; [128][64] layout, row*64+col).
__global__ __launch_bounds__(256, 2) void fused_attn(
    const ushort* __restrict__ Qp, const ushort* __restrict__ Kp,
    const ushort* __restrict__ VT, const unsigned long long* __restrict__ mb,
    const float* __restrict__ qmask, float* __restrict__ attns,
    ushort* __restrict__ concat) {
    __shared__ ushort Qs[16 * 136];        // 4.3 KB
    __shared__ ushort Ss[16 * 1032];       // 33 KB exp'd scores, stride pad 8
    __shared__ ushort KV[2][8192];         // 2 x 16KB staged K/V tiles
    __shared__ unsigned Ms[16][34];        // bitpacked mask tile
    __shared__ float rowpart[16][5];
    __shared__ float scale_s[16];

    int bid = blockIdx.x;
    const int h = bid & 7;                 // XCD-pinned head -> K/VT L2-resident
    int t = bid >> 3;
    const int b = t >> 6;
    const int q0 = (t & 63) * 16;
    const int tid = threadIdx.x;
    const int w = tid >> 6, l = tid & 63;
    const int l16 = l & 15, quad = l >> 4;
    const float sc = 0.08838834764831845f;  // 1/sqrt(128)

    // ---- load Q tile (16 x 128) + mask tile ----
    {
        int row = tid >> 4, col = (tid & 15) * 8;
        *(uint4*)&Qs[row * 136 + col] =
            *(const uint4*)(Qp + (size_t)(b * 1024 + q0 + row) * 1024 + h * 128 + col);
        int pr = tid & 15;
        uint2 mv = ((const uint2*)mb)[(size_t)(b * 1024 + q0 + row) * 16 + pr];
        Ms[row][pr * 2] = mv.x;
        Ms[row][pr * 2 + 1] = mv.y;
    }
    __syncthreads();

    shortx8 af[4];
    #pragma unroll
    for (int kk = 0; kk < 4; kk++)
        af[kk] = *(const shortx8*)&Qs[l16 * 136 + kk * 32 + quad * 8];

    // K-tile staging: [64][128] ushorts. chunk rr: row = rr*16 + (tid>>4), col (tid&15)*8
    const int ksrow = tid >> 4;          // 0..15
    const int kscol = (tid & 15) * 8;    // element col 0..120
    const ushort* Kbh = Kp + (size_t)b * 1048576 + h * 128;  // + k*1024 + col

#define STAGE_K(c, buf)                                                          \
    {                                                                            \
        _Pragma("unroll")                                                        \
        for (int rr = 0; rr < 4; ++rr)                                           \
            gload16(Kbh + (size_t)((c) * 64 + rr * 16 + ksrow) * 1024 + kscol,   \
                    &KV[buf][rr * 2048 + tid * 8]);                              \
    }

    // ---- QK^T: stage(next) -> compute(cur) -> barrier ----
    float ssum[4] = {0.0f, 0.0f, 0.0f, 0.0f};
    const int bp64 = w * 16 + l16;
    const int wsel = bp64 >> 5, bitp = bp64 & 31;
    STAGE_K(0, 0);
    __syncthreads();
    int cur = 0;
    #pragma unroll 1
    for (int c = 0; c < 16; ++c) {
        if (c < 15) STAGE_K(c + 1, cur ^ 1);
        shortx8 b0 = *(const shortx8*)&KV[cur][(w * 16 + l16) * 128 + 0 * 32 + quad * 8];
        shortx8 b1 = *(const shortx8*)&KV[cur][(w * 16 + l16) * 128 + 1 * 32 + quad * 8];
        shortx8 b2 = *(const shortx8*)&KV[cur][(w * 16 + l16) * 128 + 2 * 32 + quad * 8];
        shortx8 b3 = *(const shortx8*)&KV[cur][(w * 16 + l16) * 128 + 3 * 32 + quad * 8];
        floatx4 acc = {0.0f, 0.0f, 0.0f, 0.0f};
        __builtin_amdgcn_s_setprio(1);
        acc = __builtin_amdgcn_mfma_f32_16x16x32_bf16(af[0], b0, acc, 0, 0, 0);
        acc = __builtin_amdgcn_mfma_f32_16x16x32_bf16(af[1], b1, acc, 0, 0, 0);
        acc = __builtin_amdgcn_mfma_f32_16x16x32_bf16(af[2], b2, acc, 0, 0, 0);
        acc = __builtin_amdgcn_mfma_f32_16x16x32_bf16(af[3], b3, acc, 0, 0, 0);
        __builtin_amdgcn_s_setprio(0);
        int k0 = c * 64 + w * 16;
        #pragma unroll
        for (int r = 0; r < 4; ++r) {
            int q = quad * 4 + r;
            unsigned wv = Ms[q][c * 2 + wsel];
            float v = ((wv >> bitp) & 1u) ? 0.0f : __expf(acc[r] * sc);
            ssum[r] += v;
            Ss[q * 1032 + k0 + l16] = f2bf(v);
        }
        __syncthreads();   // lands next stage, syncs Ss/KV
        cur ^= 1;
    }

    // V-tile staging: [128][64] ushorts. chunk rr: row = rr*32 + (tid>>3), col (tid&7)*8
    const int vsrow = tid >> 3;          // 0..31
    const int vscol = (tid & 7) * 8;     // 0..56
    const ushort* Vbh = VT + (size_t)(h * 8 + b) * 131072;  // + d*1024 + k

#define STAGE_V(c, buf)                                                          \
    {                                                                            \
        _Pragma("unroll")                                                        \
        for (int rr = 0; rr < 4; ++rr)                                           \
            gload16(Vbh + (size_t)(rr * 32 + vsrow) * 1024 + (c) * 64 + vscol,   \
                    &KV[buf][rr * 2048 + tid * 8]);                              \
    }

    STAGE_V(0, 0);   // lands under the row-sum reduction

    // ---- row sums: butterfly over 16-lane group, combine 4 waves via LDS ----
    #pragma unroll
    for (int r = 0; r < 4; ++r) {
        float s = ssum[r];
        #pragma unroll
        for (int off = 1; off < 16; off <<= 1) s += __shfl_xor(s, off, 16);
        ssum[r] = s;
    }
    if (l16 == 0) {
        #pragma unroll
        for (int r = 0; r < 4; ++r) rowpart[quad * 4 + r][w] = ssum[r];
    }
    __syncthreads();    // also lands V tile 0
    if (tid < 16) {
        float s = rowpart[tid][0] + rowpart[tid][1] + rowpart[tid][2] + rowpart[tid][3];
        scale_s[tid] = qmask[b * 1024 + q0 + tid] / s;
    }
    __syncthreads();

    // ---- PV: O = P @ V from staged LDS tiles ----
    floatx4 o0 = {0.0f, 0.0f, 0.0f, 0.0f}, o1 = {0.0f, 0.0f, 0.0f, 0.0f};
    cur = 0;
    #pragma unroll 1
    for (int cc = 0; cc < 16; ++cc) {
        if (cc < 15) STAGE_V(cc + 1, cur ^ 1);
        shortx8 pa0 = *(const shortx8*)&Ss[l16 * 1032 + cc * 64 + quad * 8];
        shortx8 pa1 = *(const shortx8*)&Ss[l16 * 1032 + cc * 64 + 32 + quad * 8];
        shortx8 v00 = *(const shortx8*)&KV[cur][(w * 32 + l16) * 64 + 0 * 32 + quad * 8];
        shortx8 v01 = *(const shortx8*)&KV[cur][(w * 32 + 16 + l16) * 64 + 0 * 32 + quad * 8];
        shortx8 v10 = *(const shortx8*)&KV[cur][(w * 32 + l16) * 64 + 1 * 32 + quad * 8];
        shortx8 v11 = *(const shortx8*)&KV[cur][(w * 32 + 16 + l16) * 64 + 1 * 32 + quad * 8];
        __builtin_amdgcn_s_setprio(1);
        o0 = __builtin_amdgcn_mfma_f32_16x16x32_bf16(pa0, v00, o0, 0, 0, 0);
        o1 = __builtin_amdgcn_mfma_f32_16x16x32_bf16(pa0, v01, o1, 0, 0, 0);
        o0 = __builtin_amdgcn_mfma_f32_16x16x32_bf16(pa1, v10, o0, 0, 0, 0);
        o1 = __builtin_amdgcn_mfma_f32_16x16x32_bf16(pa1, v11, o1, 0, 0, 0);
        __builtin_amdgcn_s_setprio(0);
        __syncthreads();
        cur ^= 1;
    }

    // ---- all global stores at the end ----
    #pragma unroll
    for (int r = 0; r < 4; ++r) {
        int q = quad * 4 + r;
        float scl = scale_s[q];
        int d = w * 32 + l16;
        size_t base = (size_t)(b * 1024 + q0 + q) * 2048 + 1024 + h * 128;
        concat[base + d]      = f2bf(o0[r] * scl);
        concat[base + d + 16] = f2bf(o1[r] * scl);
    }
    {
        int row = tid >> 4;
        float scl = scale_s[row];
        float* arow = attns + ((size_t)((h * 8 + b) * 1024 + q0 + row)) * 1024;
        int c0 = (tid & 15) * 4;
        #pragma unroll
        for (int j = 0; j < 16; ++j) {
            int c = c0 + j * 64;
            ushort4 v = *(const ushort4*)&Ss[row * 1032 + c];
            floatx4 o;
            o.x = bf2f(v.x) * scl;
            o.y = bf2f(v.y) * scl;
            o.z = bf2f(v.z) * scl;
            o.w = bf2f(v.w) * scl;
            __builtin_nontemporal_store(o, (floatx4*)(arow + c));
        }
    }
}

// ---------------- LayerNorm epilogue: x = LN(ffn0 + ffn1 + bf + decoder) ----------------
__global__ __launch_bounds__(256) void ln_out(const float* __restrict__ ffn0,
                                              const float* __restrict__ ffn1,
                                              const float* __restrict__ dec,
                                              const float* __restrict__ bfv,
                                              const float* __restrict__ gamma,
                                              const float* __restrict__ beta,
                                              float* __restrict__ out) {
    __shared__ float sb[8];
    int row = blockIdx.x, tid = threadIdx.x;
    int c = tid * 4;
    size_t base = (size_t)row * 1024 + c;
    float4 x = *(const float4*)(ffn0 + base);
    float4 y = *(const float4*)(ffn1 + base);
    float4 d = *(const float4*)(dec + base);
    float4 bb = *(const float4*)(bfv + c);
    x.x += y.x + d.x + bb.x; x.y += y.y + d.y + bb.y;
    x.z += y.z + d.z + bb.z; x.w += y.w + d.w + bb.w;

    float s = x.x + x.y + x.z + x.w;
    float s2 = x.x * x.x + x.y * x.y + x.z * x.z + x.w * x.w;
    #pragma unroll
    for (int o = 32; o; o >>= 1) {
        s += __shfl_down(s, o, 64);
        s2 += __shfl_down(s2, o, 64);
    }
    if ((tid & 63) == 0) { sb[tid >> 6] = s; sb[4 + (tid >> 6)] = s2; }
    __syncthreads();
    s = sb[0] + sb[1] + sb[2] + sb[3];
    s2 = sb[4] + sb[5] + sb[6] + sb[7];
    float mu = s * (1.0f / 1024.0f);
    float var = s2 * (1.0f / 1024.0f) - mu * mu;
    float rs = rsqrtf(var + 1e-5f);

    float4 g = *(const float4*)(gamma + c);
    float4 be = *(const float4*)(beta + c);
    float4 o4;
    o4.x = (x.x - mu) * rs * g.x + be.x;
    o4.y = (x.y - mu) * rs * g.y + be.y;
    o4.z = (x.z - mu) * rs * g.z + be.z;
    o4.w = (x.w - mu) * rs * g.w + be.w;
    *(float4*)(out + base) = o4;
}

extern "C" void kernel_launch(void* const* d_in, const int* in_sizes, int n_in,
                              void* d_out, int out_size, void* d_ws, size_t ws_size,
                              hipStream_t stream) {
    const float* memory  = (const float*)d_in[0];   // (8,1024,1024)
    const float* decoder = (const float*)d_in[1];   // (8,1024,1024)
    const float* qmask   = (const float*)d_in[2];   // (8,1024)
    const float* Wk      = (const float*)d_in[3];   // (1024,1024)
    const float* Wv      = (const float*)d_in[4];
    const float* Wq      = (const float*)d_in[5];
    const float* Wf      = (const float*)d_in[6];   // (2048,1024)
    const float* bfv     = (const float*)d_in[7];   // (1024,)
    const float* gamma   = (const float*)d_in[8];
    const float* beta    = (const float*)d_in[9];
    const int*   mask    = (const int*)d_in[10];    // (8,1024,1024) 0/1

    float* xout  = (float*)d_out;                   // (8,1024,1024)
    float* attns = xout + 8388608LL;                // (64,1024,1024)

    char* w = (char*)d_ws;
    ushort* mem_bf = (ushort*)(w + 0);              // 16 MB [cast -> proj]
    ushort* Kp     = (ushort*)(w + (16LL << 20));   // 16 MB [proj -> fused]
    ushort* Qp     = (ushort*)(w + (32LL << 20));   // 16 MB [proj -> fused]
    ushort* Vp     = (ushort*)(w + (48LL << 20));   // 16 MB [proj -> vtrans]
    ushort* VT     = (ushort*)(w + (64LL << 20));   // 16 MB [vtrans -> fused]
    ushort* concat = (ushort*)(w + (80LL << 20));   // 32 MB [cast -> ffn]
    ushort* WkT    = (ushort*)(w + (112LL << 20));  // 2 MB
    ushort* WvT    = (ushort*)(w + (114LL << 20));  // 2 MB
    ushort* WqT    = (ushort*)(w + (116LL << 20));  // 2 MB
    ushort* WfT    = (ushort*)(w + (118LL << 20));  // 4 MB
    unsigned long long* mbits = (unsigned long long*)(w + (122LL << 20));  // 1 MB [cast -> fused]
    // overlays (lifetime-disjoint):
    float* ffn0 = (float*)(w + 0);                  // 32 MB over mem_bf+Kp (dead after fused)
    float* ffn1 = (float*)(w + (32LL << 20));       // 32 MB over Qp+Vp (dead after fused)

    // 1) casts + mask bitpack (merged)
    cast_pack<<<10240, 256, 0, stream>>>(memory, decoder, mask, mem_bf, concat, mbits);
    // 2) all weight transposes (one launch)
    wtrans_all<<<dim3(32, 32, 5), dim3(32, 8), 0, stream>>>(Wk, Wv, Wq, Wf, WkT, WvT, WqT, WfT);
    // 3) three projections, XCD-swizzled
    gemm_proj3<<<1536, 256, 0, stream>>>(mem_bf, concat, WkT, WvT, WqT, Kp, Vp, Qp);
    // 4) V transpose per (b,h)
    vtrans<<<dim3(32, 4, 64), dim3(32, 8), 0, stream>>>(Vp, VT);
    // 5) fused QK^T+softmax+qmask -> attns, and PV -> concat right half (LDS-staged)
    fused_attn<<<4096, 256, 0, stream>>>(Qp, Kp, VT, mbits, qmask, attns, concat);
    // 6) FFN split-K, XCD-swizzled
    gemm_ffn<<<1024, 256, 0, stream>>>(concat, WfT, ffn0, ffn1);
    // 7) bias + residual + LayerNorm -> x output
    ln_out<<<8192, 256, 0, stream>>>(ffn0, ffn1, decoder, bfv, gamma, beta, xout);
}

// Round 8
// 709.017 us; speedup vs baseline: 1.1377x; 1.0606x over previous
//
#include <hip/hip_runtime.h>
#include <hip/hip_bf16.h>
#include <stdint.h>

typedef __attribute__((ext_vector_type(4))) float  floatx4;
typedef __attribute__((ext_vector_type(8))) short  shortx8;

__device__ __forceinline__ unsigned short f2bf(float f) {
    unsigned int u = __builtin_bit_cast(unsigned int, f);
    u += 0x7FFFu + ((u >> 16) & 1u);
    return (unsigned short)(u >> 16);
}
__device__ __forceinline__ float bf2f(unsigned short h) {
    unsigned int u = (unsigned int)h << 16;
    return __builtin_bit_cast(float, u);
}

__device__ __forceinline__ uint4 pack8(float4 a, float4 b) {
    uint4 r;
    r.x = (unsigned)f2bf(a.x) | ((unsigned)f2bf(a.y) << 16);
    r.y = (unsigned)f2bf(a.z) | ((unsigned)f2bf(a.w) << 16);
    r.z = (unsigned)f2bf(b.x) | ((unsigned)f2bf(b.y) << 16);
    r.w = (unsigned)f2bf(b.z) | ((unsigned)f2bf(b.w) << 16);
    return r;
}

// async global->LDS, 16B per lane. LDS dest must be (wave-uniform base + lane*16).
__device__ __forceinline__ void gload16(const ushort* g, ushort* l) {
    __builtin_amdgcn_global_load_lds(
        (const __attribute__((address_space(1))) unsigned int*)g,
        (__attribute__((address_space(3))) unsigned int*)l, 16, 0, 0);
}

// ------- merged cast+pack: memory->bf16, decoder->concat left, mask->bits -------
__global__ __launch_bounds__(256) void cast_pack(const float* __restrict__ mem,
                                                 const float* __restrict__ dec,
                                                 const int* __restrict__ mask,
                                                 ushort* __restrict__ mem_bf,
                                                 ushort* __restrict__ concat,
                                                 unsigned long long* __restrict__ mb) {
    int bx = blockIdx.x;
    if (bx < 4096) {
        long long i = ((long long)bx * 256 + threadIdx.x) * 8;
        const float4* p = (const float4*)(mem + i);
        *(uint4*)(mem_bf + i) = pack8(p[0], p[1]);
    } else if (bx < 8192) {
        long long i = ((long long)(bx - 4096) * 256 + threadIdx.x) * 8;
        long long r = i >> 10, c = i & 1023;
        const float4* p = (const float4*)(dec + i);
        *(uint4*)(concat + r * 2048 + c) = pack8(p[0], p[1]);
    } else {
        int gw = ((bx - 8192) * 256 + threadIdx.x) >> 6;   // 0..8191
        int l = threadIdx.x & 63;
        #pragma unroll
        for (int i = 0; i < 16; ++i) {
            size_t widx = (size_t)gw * 16 + i;
            unsigned long long m = __ballot(mask[widx * 64 + l] != 0);
            if (l == 0) mb[widx] = m;
        }
    }
}

// ------- all weight transpose-casts in one launch: z 0-2 = 1024^2, z 3-4 = Wf halves ---
__global__ __launch_bounds__(256) void wtrans_all(const float* __restrict__ W0,
                                                  const float* __restrict__ W1,
                                                  const float* __restrict__ W2,
                                                  const float* __restrict__ W3,
                                                  ushort* __restrict__ T0,
                                                  ushort* __restrict__ T1,
                                                  ushort* __restrict__ T2,
                                                  ushort* __restrict__ T3) {
    __shared__ float t[32][33];
    int z = blockIdx.z;
    const float* W; ushort* WT; int K, byb;
    if (z == 0)      { W = W0; WT = T0; K = 1024; byb = blockIdx.y; }
    else if (z == 1) { W = W1; WT = T1; K = 1024; byb = blockIdx.y; }
    else if (z == 2) { W = W2; WT = T2; K = 1024; byb = blockIdx.y; }
    else             { W = W3; WT = T3; K = 2048; byb = blockIdx.y + (z - 3) * 32; }
    int tx = threadIdx.x, ty = threadIdx.y;
    int bx = blockIdx.x * 32;   // n
    int by = byb * 32;          // k
    #pragma unroll
    for (int i = 0; i < 4; i++)
        t[ty + 8 * i][tx] = W[(size_t)(by + ty + 8 * i) * 1024 + bx + tx];
    __syncthreads();
    #pragma unroll
    for (int i = 0; i < 4; i++)
        WT[(size_t)(bx + ty + 8 * i) * K + by + tx] = f2bf(t[tx][ty + 8 * i]);
}

// ---------------- V transpose per (b,h): V[(b*1024+k)*1024+h*128+d] -> VT[((h*8+b)*128+d)*1024+k]
__global__ __launch_bounds__(256) void vtrans(const ushort* __restrict__ V,
                                              ushort* __restrict__ VT) {
    __shared__ ushort t[32][33];
    int tx = threadIdx.x, ty = threadIdx.y;
    int bk = blockIdx.x * 32;  // k
    int bd = blockIdx.y * 32;  // d
    int z = blockIdx.z;
    int b = z >> 3, h = z & 7;
    #pragma unroll
    for (int i = 0; i < 4; i++)
        t[ty + 8 * i][tx] = V[((size_t)(b * 1024 + bk + ty + 8 * i)) * 1024 + h * 128 + bd + tx];
    __syncthreads();
    #pragma unroll
    for (int i = 0; i < 4; i++)
        VT[((size_t)((h * 8 + b) * 128 + bd + ty + 8 * i)) * 1024 + bk + tx] = t[tx][ty + 8 * i];
}

// ---------------- shared GEMM core: C[m][n] = sum_k A[m][k]*Bt[n][k] --------------------
template <typename TC>
__device__ __forceinline__ void gemm_core(ushort* As, ushort* Bs,
                                          const ushort* __restrict__ A,
                                          const ushort* __restrict__ Bt, TC* __restrict__ C,
                                          int kbeg, int kend, int lda, int ldb, int ldc,
                                          int bm, int bn) {
    int tid = threadIdx.x;
    int l = tid & 63, wid = tid >> 6;
    int l16 = l & 15, quad = l >> 4;
    int wm = (wid & 1) * 64, wn = (wid >> 1) * 64;
    int srow = tid >> 3;          // 0..31
    int scol = (tid & 7) * 8;     // 0..56

    floatx4 acc[4][4];
    #pragma unroll
    for (int i = 0; i < 4; i++)
        #pragma unroll
        for (int j = 0; j < 4; j++)
            acc[i][j] = {0.0f, 0.0f, 0.0f, 0.0f};

    for (int kt = kbeg; kt < kend; kt += 64) {
        #pragma unroll
        for (int it = 0; it < 4; it++) {
            int row = it * 32 + srow;
            gload16(A + (size_t)(bm + row) * lda + kt + scol, &As[row * 64 + scol]);
            gload16(Bt + (size_t)(bn + row) * ldb + kt + scol, &Bs[row * 64 + scol]);
        }
        __syncthreads();
        #pragma unroll
        for (int kk = 0; kk < 64; kk += 32) {
            shortx8 af[4], bfr[4];
            #pragma unroll
            for (int i = 0; i < 4; i++)
                af[i] = *(const shortx8*)&As[(wm + i * 16 + l16) * 64 + kk + quad * 8];
            #pragma unroll
            for (int j = 0; j < 4; j++)
                bfr[j] = *(const shortx8*)&Bs[(wn + j * 16 + l16) * 64 + kk + quad * 8];
            #pragma unroll
            for (int i = 0; i < 4; i++)
                #pragma unroll
                for (int j = 0; j < 4; j++)
                    acc[i][j] = __builtin_amdgcn_mfma_f32_16x16x32_bf16(af[i], bfr[j], acc[i][j], 0, 0, 0);
        }
        __syncthreads();
    }

    #pragma unroll
    for (int i = 0; i < 4; i++) {
        #pragma unroll
        for (int j = 0; j < 4; j++) {
            int row0 = bm + wm + i * 16 + quad * 4;
            int col = bn + wn + j * 16 + l16;
            #pragma unroll
            for (int r = 0; r < 4; r++) {
                float v = acc[i][j][r];
                size_t idx = (size_t)(row0 + r) * ldc + col;
                if constexpr (__is_same(TC, float)) C[idx] = v;
                else C[idx] = f2bf(v);
            }
        }
    }
}

// three projections, 1D grid with XCD-aware decode
__global__ __launch_bounds__(256) void gemm_proj3(
    const ushort* __restrict__ mem_bf, const ushort* __restrict__ concat,
    const ushort* __restrict__ WkT, const ushort* __restrict__ WvT,
    const ushort* __restrict__ WqT,
    ushort* __restrict__ Kp, ushort* __restrict__ Vp, ushort* __restrict__ Qp) {
    __shared__ ushort As[128 * 64];
    __shared__ ushort Bs[128 * 64];
    int bid = blockIdx.x;
    int z = bid >> 9;             // 0..2
    int r = bid & 511;
    int xcd = r & 7, i = r >> 3;
    int m = xcd * 8 + (i & 7), n = i >> 3;
    const ushort* A; const ushort* Bt; ushort* C; int lda;
    if (z == 0)      { A = mem_bf; Bt = WkT; C = Kp; lda = 1024; }
    else if (z == 1) { A = mem_bf; Bt = WvT; C = Vp; lda = 1024; }
    else             { A = concat; Bt = WqT; C = Qp; lda = 2048; }
    gemm_core<ushort>(As, Bs, A, Bt, C, 0, 1024, lda, 1024, 1024, m * 128, n * 128);
}

// FFN split-K (z halves of K=2048), same XCD-aware decode
__global__ __launch_bounds__(256) void gemm_ffn(
    const ushort* __restrict__ concat, const ushort* __restrict__ WfT,
    float* __restrict__ ffn0, float* __restrict__ ffn1) {
    __shared__ ushort As[128 * 64];
    __shared__ ushort Bs[128 * 64];
    int bid = blockIdx.x;
    int z = bid >> 9;
    int r = bid & 511;
    int xcd = r & 7, i = r >> 3;
    int m = xcd * 8 + (i & 7), n = i >> 3;
    gemm_core<float>(As, Bs, concat, WfT, z ? ffn1 : ffn0,
                     z * 1024, z * 1024 + 1024, 2048, 2048, 1024, m * 128, n * 128);
}

// ---------------- fused attention ----------------
// R6 showed SQ_LDS_BANK_CONFLICT 44.3M: K/V tile rows are multiples of 128B so every
// 8-lane ds_read_b128 phase hit one 4-bank group (8-way). Fix per rule #21: LDS dest
// stays linear (gload_lds requirement); the GLOBAL source column is pre-swizzled
// (col ^= (row&7)<<3 elements) and the ds_read applies the same XOR. Q tile now loads
// per-lane direct from global (no LDS, one barrier less).
__global__ __launch_bounds__(256, 2) void fused_attn(
    const ushort* __restrict__ Qp, const ushort* __restrict__ Kp,
    const ushort* __restrict__ VT, const unsigned long long* __restrict__ mb,
    const float* __restrict__ qmask, float* __restrict__ attns,
    ushort* __restrict__ concat) {
    __shared__ ushort Ss[16 * 1032];       // 33 KB exp'd scores, stride pad 8
    __shared__ ushort KV[2][8192];         // 2 x 16KB staged K/V tiles
    __shared__ unsigned Ms[16][34];        // bitpacked mask tile
    __shared__ float rowpart[16][5];
    __shared__ float scale_s[16];

    int bid = blockIdx.x;
    const int h = bid & 7;                 // XCD-pinned head -> K/VT L2-resident
    int t = bid >> 3;
    const int b = t >> 6;
    const int q0 = (t & 63) * 16;
    const int tid = threadIdx.x;
    const int w = tid >> 6, l = tid & 63;
    const int l16 = l & 15, quad = l >> 4;
    const float sc = 0.08838834764831845f;  // 1/sqrt(128)

    // ---- mask tile to LDS; Q fragments per-lane direct from global ----
    {
        int row = tid >> 4, pr = tid & 15;
        uint2 mv = ((const uint2*)mb)[(size_t)(b * 1024 + q0 + row) * 16 + pr];
        Ms[row][pr * 2] = mv.x;
        Ms[row][pr * 2 + 1] = mv.y;
    }
    shortx8 af[4];
    {
        const ushort* Qr = Qp + (size_t)(b * 1024 + q0 + l16) * 1024 + h * 128 + quad * 8;
        #pragma unroll
        for (int kk = 0; kk < 4; kk++)
            af[kk] = *(const shortx8*)(Qr + kk * 32);
    }

    // K-tile staging: logical [64][128] ushorts, linear LDS; source col pre-swizzled.
    const int ksrow = tid >> 4;                                   // 0..15
    const int kswcol = ((tid & 15) * 8) ^ ((ksrow & 7) << 3);     // swizzled source col
    const ushort* Kbh = Kp + (size_t)b * 1048576 + h * 128;

#define STAGE_K(c, buf)                                                          \
    {                                                                            \
        _Pragma("unroll")                                                        \
        for (int rr = 0; rr < 4; ++rr)                                           \
            gload16(Kbh + (size_t)((c) * 64 + rr * 16 + ksrow) * 1024 + kswcol,  \
                    &KV[buf][rr * 2048 + tid * 8]);                              \
    }

    // ---- QK^T: stage(next) -> compute(cur, swizzled reads) -> barrier ----
    float ssum[4] = {0.0f, 0.0f, 0.0f, 0.0f};
    const int bp64 = w * 16 + l16;
    const int wsel = bp64 >> 5, bitp = bp64 & 31;
    const int ksw = (l16 & 7) << 3;        // read-side XOR (row&7 == l16&7)
    const int krow = (w * 16 + l16) * 128;
    STAGE_K(0, 0);
    __syncthreads();                       // covers Ms + K tile 0
    int cur = 0;
    #pragma unroll 1
    for (int c = 0; c < 16; ++c) {
        if (c < 15) STAGE_K(c + 1, cur ^ 1);
        shortx8 b0 = *(const shortx8*)&KV[cur][krow + ((0 * 32 + quad * 8) ^ ksw)];
        shortx8 b1 = *(const shortx8*)&KV[cur][krow + ((1 * 32 + quad * 8) ^ ksw)];
        shortx8 b2 = *(const shortx8*)&KV[cur][krow + ((2 * 32 + quad * 8) ^ ksw)];
        shortx8 b3 = *(const shortx8*)&KV[cur][krow + ((3 * 32 + quad * 8) ^ ksw)];
        floatx4 acc = {0.0f, 0.0f, 0.0f, 0.0f};
        __builtin_amdgcn_s_setprio(1);
        acc = __builtin_amdgcn_mfma_f32_16x16x32_bf16(af[0], b0, acc, 0, 0, 0);
        acc = __builtin_amdgcn_mfma_f32_16x16x32_bf16(af[1], b1, acc, 0, 0, 0);
        acc = __builtin_amdgcn_mfma_f32_16x16x32_bf16(af[2], b2, acc, 0, 0, 0);
        acc = __builtin_amdgcn_mfma_f32_16x16x32_bf16(af[3], b3, acc, 0, 0, 0);
        __builtin_amdgcn_s_setprio(0);
        int k0 = c * 64 + w * 16;
        #pragma unroll
        for (int r = 0; r < 4; ++r) {
            int q = quad * 4 + r;
            unsigned wv = Ms[q][c * 2 + wsel];
            float v = ((wv >> bitp) & 1u) ? 0.0f : __expf(acc[r] * sc);
            ssum[r] += v;
            Ss[q * 1032 + k0 + l16] = f2bf(v);
        }
        __syncthreads();   // lands next stage, syncs Ss/KV
        cur ^= 1;
    }

    // V-tile staging: logical [128][64] ushorts, linear LDS; source col pre-swizzled.
    const int vsrow = tid >> 3;                                   // 0..31
    const int vswcol = ((tid & 7) * 8) ^ ((vsrow & 7) << 3);      // swizzled source col
    const ushort* Vbh = VT + (size_t)(h * 8 + b) * 131072;

#define STAGE_V(c, buf)                                                          \
    {                                                                            \
        _Pragma("unroll")                                                        \
        for (int rr = 0; rr < 4; ++rr)                                           \
            gload16(Vbh + (size_t)(rr * 32 + vsrow) * 1024 + (c) * 64 + vswcol,  \
                    &KV[buf][rr * 2048 + tid * 8]);                              \
    }

    STAGE_V(0, 0);   // lands under the row-sum reduction

    // ---- row sums: butterfly over 16-lane group, combine 4 waves via LDS ----
    #pragma unroll
    for (int r = 0; r < 4; ++r) {
        float s = ssum[r];
        #pragma unroll
        for (int off = 1; off < 16; off <<= 1) s += __shfl_xor(s, off, 16);
        ssum[r] = s;
    }
    if (l16 == 0) {
        #pragma unroll
        for (int r = 0; r < 4; ++r) rowpart[quad * 4 + r][w] = ssum[r];
    }
    __syncthreads();    // also lands V tile 0
    if (tid < 16) {
        float s = rowpart[tid][0] + rowpart[tid][1] + rowpart[tid][2] + rowpart[tid][3];
        scale_s[tid] = qmask[b * 1024 + q0 + tid] / s;
    }
    __syncthreads();

    // ---- PV: O = P @ V from staged LDS tiles (swizzled reads) ----
    const int vsw = (l16 & 7) << 3;
    const int vrowA = (w * 32 + l16) * 64;        // j=0 rows
    const int vrowB = (w * 32 + 16 + l16) * 64;   // j=1 rows
    floatx4 o0 = {0.0f, 0.0f, 0.0f, 0.0f}, o1 = {0.0f, 0.0f, 0.0f, 0.0f};
    cur = 0;
    #pragma unroll 1
    for (int cc = 0; cc < 16; ++cc) {
        if (cc < 15) STAGE_V(cc + 1, cur ^ 1);
        shortx8 pa0 = *(const shortx8*)&Ss[l16 * 1032 + cc * 64 + quad * 8];
        shortx8 pa1 = *(const shortx8*)&Ss[l16 * 1032 + cc * 64 + 32 + quad * 8];
        shortx8 v00 = *(const shortx8*)&KV[cur][vrowA + ((0 * 32 + quad * 8) ^ vsw)];
        shortx8 v01 = *(const shortx8*)&KV[cur][vrowB + ((0 * 32 + quad * 8) ^ vsw)];
        shortx8 v10 = *(const shortx8*)&KV[cur][vrowA + ((1 * 32 + quad * 8) ^ vsw)];
        shortx8 v11 = *(const shortx8*)&KV[cur][vrowB + ((1 * 32 + quad * 8) ^ vsw)];
        __builtin_amdgcn_s_setprio(1);
        o0 = __builtin_amdgcn_mfma_f32_16x16x32_bf16(pa0, v00, o0, 0, 0, 0);
        o1 = __builtin_amdgcn_mfma_f32_16x16x32_bf16(pa0, v01, o1, 0, 0, 0);
        o0 = __builtin_amdgcn_mfma_f32_16x16x32_bf16(pa1, v10, o0, 0, 0, 0);
        o1 = __builtin_amdgcn_mfma_f32_16x16x32_bf16(pa1, v11, o1, 0, 0, 0);
        __builtin_amdgcn_s_setprio(0);
        __syncthreads();
        cur ^= 1;
    }

    // ---- all global stores at the end ----
    #pragma unroll
    for (int r = 0; r < 4; ++r) {
        int q = quad * 4 + r;
        float scl = scale_s[q];
        int d = w * 32 + l16;
        size_t base = (size_t)(b * 1024 + q0 + q) * 2048 + 1024 + h * 128;
        concat[base + d]      = f2bf(o0[r] * scl);
        concat[base + d + 16] = f2bf(o1[r] * scl);
    }
    {
        int row = tid >> 4;
        float scl = scale_s[row];
        float* arow = attns + ((size_t)((h * 8 + b) * 1024 + q0 + row)) * 1024;
        int c0 = (tid & 15) * 4;
        #pragma unroll
        for (int j = 0; j < 16; ++j) {
            int c = c0 + j * 64;
            ushort4 v = *(const ushort4*)&Ss[row * 1032 + c];
            floatx4 o;
            o.x = bf2f(v.x) * scl;
            o.y = bf2f(v.y) * scl;
            o.z = bf2f(v.z) * scl;
            o.w = bf2f(v.w) * scl;
            __builtin_nontemporal_store(o, (floatx4*)(arow + c));
        }
    }
}

// ---------------- LayerNorm epilogue: x = LN(ffn0 + ffn1 + bf + decoder) ----------------
__global__ __launch_bounds__(256) void ln_out(const float* __restrict__ ffn0,
                                              const float* __restrict__ ffn1,
                                              const float* __restrict__ dec,
                                              const float* __restrict__ bfv,
                                              const float* __restrict__ gamma,
                                              const float* __restrict__ beta,
                                              float* __restrict__ out) {
    __shared__ float sb[8];
    int row = blockIdx.x, tid = threadIdx.x;
    int c = tid * 4;
    size_t base = (size_t)row * 1024 + c;
    float4 x = *(const float4*)(ffn0 + base);
    float4 y = *(const float4*)(ffn1 + base);
    float4 d = *(const float4*)(dec + base);
    float4 bb = *(const float4*)(bfv + c);
    x.x += y.x + d.x + bb.x; x.y += y.y + d.y + bb.y;
    x.z += y.z + d.z + bb.z; x.w += y.w + d.w + bb.w;

    float s = x.x + x.y + x.z + x.w;
    float s2 = x.x * x.x + x.y * x.y + x.z * x.z + x.w * x.w;
    #pragma unroll
    for (int o = 32; o; o >>= 1) {
        s += __shfl_down(s, o, 64);
        s2 += __shfl_down(s2, o, 64);
    }
    if ((tid & 63) == 0) { sb[tid >> 6] = s; sb[4 + (tid >> 6)] = s2; }
    __syncthreads();
    s = sb[0] + sb[1] + sb[2] + sb[3];
    s2 = sb[4] + sb[5] + sb[6] + sb[7];
    float mu = s * (1.0f / 1024.0f);
    float var = s2 * (1.0f / 1024.0f) - mu * mu;
    float rs = rsqrtf(var + 1e-5f);

    float4 g = *(const float4*)(gamma + c);
    float4 be = *(const float4*)(beta + c);
    float4 o4;
    o4.x = (x.x - mu) * rs * g.x + be.x;
    o4.y = (x.y - mu) * rs * g.y + be.y;
    o4.z = (x.z - mu) * rs * g.z + be.z;
    o4.w = (x.w - mu) * rs * g.w + be.w;
    *(float4*)(out + base) = o4;
}

extern "C" void kernel_launch(void* const* d_in, const int* in_sizes, int n_in,
                              void* d_out, int out_size, void* d_ws, size_t ws_size,
                              hipStream_t stream) {
    const float* memory  = (const float*)d_in[0];   // (8,1024,1024)
    const float* decoder = (const float*)d_in[1];   // (8,1024,1024)
    const float* qmask   = (const float*)d_in[2];   // (8,1024)
    const float* Wk      = (const float*)d_in[3];   // (1024,1024)
    const float* Wv      = (const float*)d_in[4];
    const float* Wq      = (const float*)d_in[5];
    const float* Wf      = (const float*)d_in[6];   // (2048,1024)
    const float* bfv     = (const float*)d_in[7];   // (1024,)
    const float* gamma   = (const float*)d_in[8];
    const float* beta    = (const float*)d_in[9];
    const int*   mask    = (const int*)d_in[10];    // (8,1024,1024) 0/1

    float* xout  = (float*)d_out;                   // (8,1024,1024)
    float* attns = xout + 8388608LL;                // (64,1024,1024)

    char* w = (char*)d_ws;
    ushort* mem_bf = (ushort*)(w + 0);              // 16 MB [cast -> proj]
    ushort* Kp     = (ushort*)(w + (16LL << 20));   // 16 MB [proj -> fused]
    ushort* Qp     = (ushort*)(w + (32LL << 20));   // 16 MB [proj -> fused]
    ushort* Vp     = (ushort*)(w + (48LL << 20));   // 16 MB [proj -> vtrans]
    ushort* VT     = (ushort*)(w + (64LL << 20));   // 16 MB [vtrans -> fused]
    ushort* concat = (ushort*)(w + (80LL << 20));   // 32 MB [cast -> ffn]
    ushort* WkT    = (ushort*)(w + (112LL << 20));  // 2 MB
    ushort* WvT    = (ushort*)(w + (114LL << 20));  // 2 MB
    ushort* WqT    = (ushort*)(w + (116LL << 20));  // 2 MB
    ushort* WfT    = (ushort*)(w + (118LL << 20));  // 4 MB
    unsigned long long* mbits = (unsigned long long*)(w + (122LL << 20));  // 1 MB [cast -> fused]
    // overlays (lifetime-disjoint):
    float* ffn0 = (float*)(w + 0);                  // 32 MB over mem_bf+Kp (dead after fused)
    float* ffn1 = (float*)(w + (32LL << 20));       // 32 MB over Qp+Vp (dead after fused)

    // 1) casts + mask bitpack (merged)
    cast_pack<<<10240, 256, 0, stream>>>(memory, decoder, mask, mem_bf, concat, mbits);
    // 2) all weight transposes (one launch)
    wtrans_all<<<dim3(32, 32, 5), dim3(32, 8), 0, stream>>>(Wk, Wv, Wq, Wf, WkT, WvT, WqT, WfT);
    // 3) three projections, XCD-swizzled
    gemm_proj3<<<1536, 256, 0, stream>>>(mem_bf, concat, WkT, WvT, WqT, Kp, Vp, Qp);
    // 4) V transpose per (b,h)
    vtrans<<<dim3(32, 4, 64), dim3(32, 8), 0, stream>>>(Vp, VT);
    // 5) fused QK^T+softmax+qmask -> attns, and PV -> concat right half (LDS-staged, swizzled)
    fused_attn<<<4096, 256, 0, stream>>>(Qp, Kp, VT, mbits, qmask, attns, concat);
    // 6) FFN split-K, XCD-swizzled
    gemm_ffn<<<1024, 256, 0, stream>>>(concat, WfT, ffn0, ffn1);
    // 7) bias + residual + LayerNorm -> x output
    ln_out<<<8192, 256, 0, stream>>>(ffn0, ffn1, decoder, bfv, gamma, beta, xout);
}